// Round 1
// baseline (359.770 us; speedup 1.0000x reference)
//
#include <hip/hip_runtime.h>
#include <math.h>

// Problem constants (from reference setup_inputs)
constexpr int N = 262144;   // rows
constexpr int D = 256;      // embedding dim
constexpr int C = 64;       // number of centers
constexpr float CLAMP_MIN = 1e-12f;
constexpr float CLAMP_MAX = 1e12f;

constexpr int BLOCKS  = 512;          // 1024-thread blocks
constexpr int WPB     = 16;           // waves per block
constexpr int NWAVES  = BLOCKS * WPB; // 8192 waves
constexpr int GPW     = (N / 4) / NWAVES;  // 8 groups (of 4 rows) per wave

// Pre-kernel: one wave per center; write normalized center c/||c|| into ws.
__global__ __launch_bounds__(64) void center_normalize_kernel(
        const float* __restrict__ centers, float* __restrict__ cn) {
    const int c = blockIdx.x;
    const int lane = threadIdx.x;          // 0..63
    float4 v = reinterpret_cast<const float4*>(centers + c * D)[lane];
    float s = v.x * v.x + v.y * v.y + v.z * v.z + v.w * v.w;
    #pragma unroll
    for (int off = 32; off >= 1; off >>= 1)
        s += __shfl_xor(s, off, 64);
    const float inv = rsqrtf(fmaxf(s, 1e-24f));
    float4 o = make_float4(v.x * inv, v.y * inv, v.z * inv, v.w * inv);
    reinterpret_cast<float4*>(cn + c * D)[lane] = o;
}

// Main kernel: 16 lanes per row, 4 rows per group, 8 groups per wave.
// Changes vs previous version:
//  - plain (cached) global loads instead of __builtin_nontemporal_load:
//    on gfx950 the NT cache-policy bits risk a degraded VMEM path, and there
//    is zero intra-kernel reuse of emb so NT buys nothing.
//  - __launch_bounds__(1024, 8): force VGPR <= 64 so TWO 16-wave blocks fit
//    per CU (32 waves/CU). The manual xn[] double-buffer is dropped (it was
//    the VGPR hog); at 32 waves/CU TLP alone covers HBM latency
//    (need ~9 KB in flight per CU, have ~64 KB), and the fully-unrolled
//    group loop lets the compiler pipeline up to the register cap.
__global__ __launch_bounds__(1024, 8) void inner_cos_kernel(
        const float* __restrict__ emb,
        const int*   __restrict__ label,
        const float* __restrict__ cnormed,
        float* __restrict__ partials) {
    __shared__ float4 ctab[C * D / 4];     // 64 KiB
    __shared__ float  ssum[WPB];

    // cooperative table load: 1024 threads x 4 float4
    {
        const float4* src = reinterpret_cast<const float4*>(cnormed);
        #pragma unroll
        for (int i = 0; i < (C * D / 4) / 1024; ++i)
            ctab[threadIdx.x + i * 1024] = src[threadIdx.x + i * 1024];
    }

    const int lane = threadIdx.x & 63;
    const int wave = threadIdx.x >> 6;     // 0..15
    const int sub  = lane & 15;            // lane within 16-group
    const int quad = lane >> 4;            // which of the 4 rows in the group
    const int gwave = blockIdx.x * WPB + wave;    // 0..8191

    // Prefetch all 32 labels this wave needs:
    // lane (k*4+q) holds label of row 4*gwave + k*4*NWAVES + q, k=0..7.
    int mylab = 0;
    if (lane < 32) {
        const int k = lane >> 2, q = lane & 3;
        mylab = label[4 * gwave + k * (4 * NWAVES) + q];
    }

    __syncthreads();                       // table ready

    const float4* xbase = reinterpret_cast<const float4*>(emb);

    float lsum = 0.0f;

    #pragma unroll
    for (int k = 0; k < GPW; ++k) {
        const int row = 4 * gwave + k * (4 * NWAVES) + quad;
        const float4* xr = xbase + (size_t)row * (D / 4);
        float4 x0 = xr[sub +  0];
        float4 x1 = xr[sub + 16];
        float4 x2 = xr[sub + 32];
        float4 x3 = xr[sub + 48];

        // c from LDS: 4 x ds_read_b128, conflict-free per 16-lane phase
        const int lab = __shfl(mylab, (k << 2) + quad);
        const float4* crow = ctab + lab * (D / 4);
        float4 c0 = crow[sub +  0], c1 = crow[sub + 16];
        float4 c2 = crow[sub + 32], c3 = crow[sub + 48];

        float dot = 0.0f, nx2 = 0.0f;
        dot = fmaf(x0.x, c0.x, dot); dot = fmaf(x0.y, c0.y, dot);
        dot = fmaf(x0.z, c0.z, dot); dot = fmaf(x0.w, c0.w, dot);
        dot = fmaf(x1.x, c1.x, dot); dot = fmaf(x1.y, c1.y, dot);
        dot = fmaf(x1.z, c1.z, dot); dot = fmaf(x1.w, c1.w, dot);
        dot = fmaf(x2.x, c2.x, dot); dot = fmaf(x2.y, c2.y, dot);
        dot = fmaf(x2.z, c2.z, dot); dot = fmaf(x2.w, c2.w, dot);
        dot = fmaf(x3.x, c3.x, dot); dot = fmaf(x3.y, c3.y, dot);
        dot = fmaf(x3.z, c3.z, dot); dot = fmaf(x3.w, c3.w, dot);

        nx2 = fmaf(x0.x, x0.x, nx2); nx2 = fmaf(x0.y, x0.y, nx2);
        nx2 = fmaf(x0.z, x0.z, nx2); nx2 = fmaf(x0.w, x0.w, nx2);
        nx2 = fmaf(x1.x, x1.x, nx2); nx2 = fmaf(x1.y, x1.y, nx2);
        nx2 = fmaf(x1.z, x1.z, nx2); nx2 = fmaf(x1.w, x1.w, nx2);
        nx2 = fmaf(x2.x, x2.x, nx2); nx2 = fmaf(x2.y, x2.y, nx2);
        nx2 = fmaf(x2.z, x2.z, nx2); nx2 = fmaf(x2.w, x2.w, nx2);
        nx2 = fmaf(x3.x, x3.x, nx2); nx2 = fmaf(x3.y, x3.y, nx2);
        nx2 = fmaf(x3.z, x3.z, nx2); nx2 = fmaf(x3.w, x3.w, nx2);

        #pragma unroll
        for (int off = 8; off >= 1; off >>= 1) {
            dot += __shfl_xor(dot, off, 64);
            nx2 += __shfl_xor(nx2, off, 64);
        }
        // centers pre-normalized: cos = dot * rsqrt(||x||^2)
        float cd = 1.0f - dot * rsqrtf(fmaxf(nx2, 1e-24f));
        cd = fminf(fmaxf(cd, CLAMP_MIN), CLAMP_MAX);
        lsum += cd;          // identical across the 16 lanes of this group
    }

    // combine the 4 quads (each row counted once per 16-lane group)
    lsum += __shfl_xor(lsum, 16, 64);
    lsum += __shfl_xor(lsum, 32, 64);

    if (lane == 0) ssum[wave] = lsum;
    __syncthreads();
    if (threadIdx.x == 0) {
        float s = 0.0f;
        #pragma unroll
        for (int w = 0; w < WPB; ++w) s += ssum[w];
        partials[blockIdx.x] = s;
    }
}

// Final reduction: 512 partials -> scalar mean.
__global__ __launch_bounds__(256) void finalize_kernel(
        const float* __restrict__ partials, float* __restrict__ out) {
    float s = 0.0f;
    #pragma unroll
    for (int i = 0; i < BLOCKS / 256; ++i)
        s += partials[threadIdx.x + (i << 8)];
    #pragma unroll
    for (int off = 32; off >= 1; off >>= 1)
        s += __shfl_xor(s, off, 64);
    __shared__ float ss[4];
    if ((threadIdx.x & 63) == 0) ss[threadIdx.x >> 6] = s;
    __syncthreads();
    if (threadIdx.x == 0)
        out[0] = ((ss[0] + ss[1]) + (ss[2] + ss[3])) * (1.0f / (float)N);
}

extern "C" void kernel_launch(void* const* d_in, const int* in_sizes, int n_in,
                              void* d_out, int out_size, void* d_ws, size_t ws_size,
                              hipStream_t stream) {
    const float* emb     = (const float*)d_in[0];
    const int*   label   = (const int*)d_in[1];
    const float* centers = (const float*)d_in[2];
    float* out      = (float*)d_out;
    float* cnormed  = (float*)d_ws;                  // 64*256 floats = 64 KiB
    float* partials = (float*)d_ws + C * D;          // 512 floats

    center_normalize_kernel<<<C, 64, 0, stream>>>(centers, cnormed);
    inner_cos_kernel<<<BLOCKS, 1024, 0, stream>>>(emb, label, cnormed, partials);
    finalize_kernel<<<1, 256, 0, stream>>>(partials, out);
}

// Round 2
// 337.300 us; speedup vs baseline: 1.0666x; 1.0666x over previous
//
#include <hip/hip_runtime.h>
#include <math.h>

// Problem constants (from reference setup_inputs)
constexpr int N = 262144;   // rows
constexpr int D = 256;      // embedding dim
constexpr int C = 64;       // number of centers
constexpr float CLAMP_MIN = 1e-12f;
constexpr float CLAMP_MAX = 1e12f;

constexpr int BLOCKS  = 512;          // 1024-thread blocks
constexpr int WPB     = 16;           // waves per block
constexpr int NWAVES  = BLOCKS * WPB; // 8192 waves
constexpr int GPW     = (N / 4) / NWAVES;  // 8 groups (of 4 rows) per wave

// native clang vector type: __builtin_nontemporal_load requires it
typedef float fvec4 __attribute__((ext_vector_type(4)));

// Pre-kernel: one wave per center; write normalized center c/||c|| into ws.
__global__ __launch_bounds__(64) void center_normalize_kernel(
        const float* __restrict__ centers, float* __restrict__ cn) {
    const int c = blockIdx.x;
    const int lane = threadIdx.x;          // 0..63
    float4 v = reinterpret_cast<const float4*>(centers + c * D)[lane];
    float s = v.x * v.x + v.y * v.y + v.z * v.z + v.w * v.w;
    #pragma unroll
    for (int off = 32; off >= 1; off >>= 1)
        s += __shfl_xor(s, off, 64);
    const float inv = rsqrtf(fmaxf(s, 1e-24f));
    float4 o = make_float4(v.x * inv, v.y * inv, v.z * inv, v.w * inv);
    reinterpret_cast<float4*>(cn + c * D)[lane] = o;
}

// Main kernel: 16 lanes per row, 4 rows per group, 8 groups per wave.
// The 64 KiB normalized-center table lives in LDS (loaded once per block),
// so the ONLY VMEM traffic in the loop is the nontemporal emb stream
// (4 x dwordx4 per wave per group) + one label gather per wave.
// This is the best-measured variant (335.7 us): NT loads + 1-group-ahead
// software prefetch, no VGPR cap. Restored verbatim after the R1
// experiment (plain loads + launch_bounds(1024,8), no prefetch) regressed
// to 359.8 us.
__global__ __launch_bounds__(1024) void inner_cos_kernel(
        const float* __restrict__ emb,
        const int*   __restrict__ label,
        const float* __restrict__ cnormed,
        float* __restrict__ partials) {
    __shared__ float4 ctab[C * D / 4];     // 64 KiB
    __shared__ float  ssum[WPB];

    // cooperative table load: 1024 threads x 4 float4
    {
        const float4* src = reinterpret_cast<const float4*>(cnormed);
        #pragma unroll
        for (int i = 0; i < (C * D / 4) / 1024; ++i)
            ctab[threadIdx.x + i * 1024] = src[threadIdx.x + i * 1024];
    }

    const int lane = threadIdx.x & 63;
    const int wave = threadIdx.x >> 6;     // 0..15
    const int sub  = lane & 15;            // lane within 16-group
    const int quad = lane >> 4;            // which of the 4 rows in the group
    const int gwave = blockIdx.x * WPB + wave;    // 0..8191

    // Prefetch all 32 labels this wave needs:
    // lane (k*4+q) holds label of row 4*gwave + k*4*NWAVES + q, k=0..7.
    int mylab = 0;
    if (lane < 32) {
        const int k = lane >> 2, q = lane & 3;
        mylab = label[4 * gwave + k * (4 * NWAVES) + q];
    }

    __syncthreads();                       // table ready

    const fvec4* xbase = reinterpret_cast<const fvec4*>(emb);

    float lsum = 0.0f;
    fvec4 x[4];

    // prologue: stream group 0's x (nontemporal: no L2 churn)
    {
        const fvec4* xr = xbase + (size_t)(4 * gwave + quad) * (D / 4);
        #pragma unroll
        for (int j = 0; j < 4; ++j)
            x[j] = __builtin_nontemporal_load(xr + (j << 4) + sub);
    }

    #pragma unroll
    for (int k = 0; k < GPW; ++k) {
        fvec4 xn[4];
        if (k + 1 < GPW) {   // issue next group's x-loads before current compute
            const int rown = 4 * gwave + (k + 1) * (4 * NWAVES) + quad;
            const fvec4* xr = xbase + (size_t)rown * (D / 4);
            #pragma unroll
            for (int j = 0; j < 4; ++j)
                xn[j] = __builtin_nontemporal_load(xr + (j << 4) + sub);
        }

        // c from LDS: 4 x ds_read_b128, conflict-free per 16-lane phase
        const int lab = __shfl(mylab, (k << 2) + quad);
        const float4* crow = ctab + lab * (D / 4);
        float4 c0 = crow[sub +  0], c1 = crow[sub + 16];
        float4 c2 = crow[sub + 32], c3 = crow[sub + 48];

        float dot = 0.0f, nx2 = 0.0f;
        dot = fmaf(x[0].x, c0.x, dot); dot = fmaf(x[0].y, c0.y, dot);
        dot = fmaf(x[0].z, c0.z, dot); dot = fmaf(x[0].w, c0.w, dot);
        dot = fmaf(x[1].x, c1.x, dot); dot = fmaf(x[1].y, c1.y, dot);
        dot = fmaf(x[1].z, c1.z, dot); dot = fmaf(x[1].w, c1.w, dot);
        dot = fmaf(x[2].x, c2.x, dot); dot = fmaf(x[2].y, c2.y, dot);
        dot = fmaf(x[2].z, c2.z, dot); dot = fmaf(x[2].w, c2.w, dot);
        dot = fmaf(x[3].x, c3.x, dot); dot = fmaf(x[3].y, c3.y, dot);
        dot = fmaf(x[3].z, c3.z, dot); dot = fmaf(x[3].w, c3.w, dot);
        #pragma unroll
        for (int j = 0; j < 4; ++j) {
            nx2 = fmaf(x[j].x, x[j].x, nx2); nx2 = fmaf(x[j].y, x[j].y, nx2);
            nx2 = fmaf(x[j].z, x[j].z, nx2); nx2 = fmaf(x[j].w, x[j].w, nx2);
        }
        #pragma unroll
        for (int off = 8; off >= 1; off >>= 1) {
            dot += __shfl_xor(dot, off, 64);
            nx2 += __shfl_xor(nx2, off, 64);
        }
        // centers pre-normalized: cos = dot * rsqrt(||x||^2)
        float cd = 1.0f - dot * rsqrtf(fmaxf(nx2, 1e-24f));
        cd = fminf(fmaxf(cd, CLAMP_MIN), CLAMP_MAX);
        lsum += cd;          // identical across the 16 lanes of this group

        if (k + 1 < GPW) {
            #pragma unroll
            for (int j = 0; j < 4; ++j) x[j] = xn[j];
        }
    }

    // combine the 4 quads (each row counted once per 16-lane group)
    lsum += __shfl_xor(lsum, 16, 64);
    lsum += __shfl_xor(lsum, 32, 64);

    if (lane == 0) ssum[wave] = lsum;
    __syncthreads();
    if (threadIdx.x == 0) {
        float s = 0.0f;
        #pragma unroll
        for (int w = 0; w < WPB; ++w) s += ssum[w];
        partials[blockIdx.x] = s;
    }
}

// Final reduction: 512 partials -> scalar mean.
__global__ __launch_bounds__(256) void finalize_kernel(
        const float* __restrict__ partials, float* __restrict__ out) {
    float s = 0.0f;
    #pragma unroll
    for (int i = 0; i < BLOCKS / 256; ++i)
        s += partials[threadIdx.x + (i << 8)];
    #pragma unroll
    for (int off = 32; off >= 1; off >>= 1)
        s += __shfl_xor(s, off, 64);
    __shared__ float ss[4];
    if ((threadIdx.x & 63) == 0) ss[threadIdx.x >> 6] = s;
    __syncthreads();
    if (threadIdx.x == 0)
        out[0] = ((ss[0] + ss[1]) + (ss[2] + ss[3])) * (1.0f / (float)N);
}

extern "C" void kernel_launch(void* const* d_in, const int* in_sizes, int n_in,
                              void* d_out, int out_size, void* d_ws, size_t ws_size,
                              hipStream_t stream) {
    const float* emb     = (const float*)d_in[0];
    const int*   label   = (const int*)d_in[1];
    const float* centers = (const float*)d_in[2];
    float* out      = (float*)d_out;
    float* cnormed  = (float*)d_ws;                  // 64*256 floats = 64 KiB
    float* partials = (float*)d_ws + C * D;          // 512 floats

    center_normalize_kernel<<<C, 64, 0, stream>>>(centers, cnormed);
    inner_cos_kernel<<<BLOCKS, 1024, 0, stream>>>(emb, label, cnormed, partials);
    finalize_kernel<<<1, 256, 0, stream>>>(partials, out);
}